// Round 1
// baseline (1691.893 us; speedup 1.0000x reference)
//
#include <hip/hip_runtime.h>
#include <cmath>
#include <cstdint>
#include <cstddef>

namespace {
constexpr int kB = 4;
constexpr int kS = 2048;
constexpr int kD = 768;
constexpr int kH = 12;
constexpr int kHD = 64;
constexpr int k3D = 3 * kD;   // 2304
constexpr float kNeg = -1000000000.0f;
}

// Faithful fp32 masking affine: s = a + NEG*(1-a), no fma contraction so the
// rounding sequence matches numpy's elementwise ops.
__device__ __forceinline__ float mask_affine(float a) {
#pragma clang fp contract(off)
    const float u = 1.0f - a;
    return a + kNeg * u;
}

// ---------------------------------------------------------------------------
// fp32 tiled GEMM with bias: C[M,N] = A[M,K] @ B[K,N] + bias[N]
// BM x BN block tile, BK k-step, TM x TN per-thread microtile, 256 threads.
// ---------------------------------------------------------------------------
template <int BM, int BN, int BK, int TM, int TN>
__global__ __launch_bounds__(256)
void gemm_bias_kernel(const float* __restrict__ A, const float* __restrict__ Bm,
                      const float* __restrict__ bias, float* __restrict__ C,
                      int M, int N, int K)
{
    static_assert(BM * BN / (TM * TN) == 256, "256 threads");
    __shared__ float As[BK][BM + 1];   // A tile transposed: As[k][m]
    __shared__ float Bs[BK][BN + 1];   // Bs[k][n]

    const int tid = threadIdx.x;
    constexpr int TX = BN / TN;        // 16
    const int tx = tid % TX;
    const int ty = tid / TX;
    const int m0 = blockIdx.y * BM;
    const int n0 = blockIdx.x * BN;

    float acc[TM][TN];
#pragma unroll
    for (int i = 0; i < TM; ++i)
#pragma unroll
        for (int j = 0; j < TN; ++j) acc[i][j] = 0.0f;

    for (int k0 = 0; k0 < K; k0 += BK) {
        // stage A tile (BM x BK), store transposed
        for (int e = tid * 4; e < BM * BK; e += 1024) {
            const int row = e / BK, col = e % BK;   // col in {0,4,8,12}
            const float4 v = *reinterpret_cast<const float4*>(
                &A[(size_t)(m0 + row) * K + (k0 + col)]);
            As[col + 0][row] = v.x; As[col + 1][row] = v.y;
            As[col + 2][row] = v.z; As[col + 3][row] = v.w;
        }
        // stage B tile (BK x BN)
        for (int e = tid * 4; e < BK * BN; e += 1024) {
            const int row = e / BN, col = e % BN;
            const float4 v = *reinterpret_cast<const float4*>(
                &Bm[(size_t)(k0 + row) * N + (n0 + col)]);
            Bs[row][col + 0] = v.x; Bs[row][col + 1] = v.y;
            Bs[row][col + 2] = v.z; Bs[row][col + 3] = v.w;
        }
        __syncthreads();
#pragma unroll
        for (int kk = 0; kk < BK; ++kk) {
            float a[TM], b[TN];
#pragma unroll
            for (int i = 0; i < TM; ++i) a[i] = As[kk][ty * TM + i];
#pragma unroll
            for (int j = 0; j < TN; ++j) b[j] = Bs[kk][tx * TN + j];
#pragma unroll
            for (int i = 0; i < TM; ++i)
#pragma unroll
                for (int j = 0; j < TN; ++j)
                    acc[i][j] = fmaf(a[i], b[j], acc[i][j]);
        }
        __syncthreads();
    }

#pragma unroll
    for (int i = 0; i < TM; ++i) {
        const int m = m0 + ty * TM + i;
#pragma unroll
        for (int j = 0; j < TN; ++j) {
            const int n = n0 + tx * TN + j;
            C[(size_t)m * N + n] = acc[i][j] + bias[n];
        }
    }
}

// ---------------------------------------------------------------------------
// Degenerate-softmax attention: for each (b,h,q) row the softmax weight is an
// exact tie-average over keys whose fp32 score equals the row max (gaps are
// >= ~one ulp of 1e9 -> exp < 1.6e-28, negligible in fp32). Masked keys have
// score == -1e9 exactly and can dominate when all causal scores a <= 0.
// Block: 256 threads = 4 waves, each wave owns 4 consecutive query rows.
// ---------------------------------------------------------------------------
__global__ __launch_bounds__(256)
void attn_select_kernel(const float* __restrict__ qkv, float* __restrict__ ctx)
{
    constexpr int QPW = 4, QPB = 16, KT = 64;
    const int b = blockIdx.z, h = blockIdx.y;
    const int q0 = blockIdx.x * QPB;
    const int tid = threadIdx.x;
    const int wave = tid >> 6, lane = tid & 63;

    __shared__ float Ks[KT][65];     // +1 pad: conflict-free scalar reads
    __shared__ float Vs[KT][65];
    __shared__ float Qs[QPB][64];    // packed, float4-aligned rows

    const float* qp = qkv + (size_t)b * kS * k3D + h * kHD;
    const float* kp = qp + kD;
    const float* vp = qp + 2 * kD;

    // stage Q rows, prescaled by 1/8 (exact power of two == dividing the dot)
    {
        const int e = tid * 4;              // 0..1020, covers 16x64 floats
        const int r = e >> 6, d = e & 63;
        const float4 v = *reinterpret_cast<const float4*>(
            &qp[(size_t)(q0 + r) * k3D + d]);
        Qs[r][d + 0] = v.x * 0.125f; Qs[r][d + 1] = v.y * 0.125f;
        Qs[r][d + 2] = v.z * 0.125f; Qs[r][d + 3] = v.w * 0.125f;
    }

    float m[QPW], vsum[QPW];
    int cnt[QPW], qi[QPW];
#pragma unroll
    for (int r = 0; r < QPW; ++r) {
        m[r] = -INFINITY; vsum[r] = 0.0f; cnt[r] = 0;
        qi[r] = q0 + wave * QPW + r;
    }

    const int qmax = q0 + QPB - 1;
    const int T = qmax / KT + 1;            // causal tile count for this block
    for (int t = 0; t < T; ++t) {
        const int k0 = t * KT;
        __syncthreads();                    // protect LDS reuse (covers Qs too)
        // stage K and V tiles (64 keys x 64 dims each)
        for (int c = 0; c < 4; ++c) {
            const int idx = c * 256 + tid;  // float4 index 0..1023
            const int key = idx >> 4;
            const int d = (idx & 15) * 4;
            const float4 kv = *reinterpret_cast<const float4*>(
                &kp[(size_t)(k0 + key) * k3D + d]);
            Ks[key][d + 0] = kv.x; Ks[key][d + 1] = kv.y;
            Ks[key][d + 2] = kv.z; Ks[key][d + 3] = kv.w;
            const float4 vv = *reinterpret_cast<const float4*>(
                &vp[(size_t)(k0 + key) * k3D + d]);
            Vs[key][d + 0] = vv.x; Vs[key][d + 1] = vv.y;
            Vs[key][d + 2] = vv.z; Vs[key][d + 3] = vv.w;
        }
        __syncthreads();

        // does this wave need the tile at all? (wave-uniform)
        bool need = false;
#pragma unroll
        for (int r = 0; r < QPW; ++r)
            need = need || (k0 <= qi[r]) || (m[r] <= kNeg);
        if (!need) continue;

        float sv[QPW];
        if (k0 <= qi[QPW - 1]) {
            // lane = key index within tile; compute all 4 query dots sharing
            // each K element read.
            float dotv[QPW] = {0.f, 0.f, 0.f, 0.f};
            const float* krow = &Ks[lane][0];
            const float* qbase = &Qs[wave * QPW][0];
#pragma unroll
            for (int d = 0; d < 64; d += 4) {
                float qa[QPW][4];
#pragma unroll
                for (int r = 0; r < QPW; ++r) {
                    const float4 qv = *reinterpret_cast<const float4*>(
                        &qbase[r * 64 + d]);   // LDS broadcast, 16B
                    qa[r][0] = qv.x; qa[r][1] = qv.y;
                    qa[r][2] = qv.z; qa[r][3] = qv.w;
                }
#pragma unroll
                for (int i = 0; i < 4; ++i) {
                    const float kd = krow[d + i];
#pragma unroll
                    for (int r = 0; r < QPW; ++r)
                        dotv[r] = fmaf(qa[r][i], kd, dotv[r]);
                }
            }
#pragma unroll
            for (int r = 0; r < QPW; ++r)
                sv[r] = (k0 + lane > qi[r]) ? kNeg : mask_affine(dotv[r]);
        } else {
#pragma unroll
            for (int r = 0; r < QPW; ++r) sv[r] = kNeg;
        }

#pragma unroll
        for (int r = 0; r < QPW; ++r) {
            if (k0 > qi[r] && m[r] > kNeg) continue;   // masked & irrelevant
            const float s = sv[r];
            float tmax = s;
#pragma unroll
            for (int off = 32; off; off >>= 1)
                tmax = fmaxf(tmax, __shfl_xor(tmax, off));
            if (tmax > m[r]) { m[r] = tmax; cnt[r] = 0; vsum[r] = 0.0f; }
            unsigned long long tie = __ballot(s == m[r]);
            if (tie != 0ull) {
                cnt[r] += __popcll(tie);
                while (tie) {
                    const int j = __ffsll((unsigned long long)tie) - 1;
                    tie &= tie - 1;
                    vsum[r] += Vs[j][lane];      // lane = dim index
                }
            }
        }
    }

    // tail: keys [T*KT, S) are masked (score == -1e9 exactly) for every query
    // in this block; they matter only when the running max is <= -1e9.
    const int kstart = T * KT;
#pragma unroll
    for (int r = 0; r < QPW; ++r) {
        if (m[r] <= kNeg && kstart < kS) {
            if (m[r] < kNeg) { m[r] = kNeg; cnt[r] = 0; vsum[r] = 0.0f; }
            cnt[r] += kS - kstart;
#pragma unroll 8
            for (int k = kstart; k < kS; ++k)
                vsum[r] += vp[(size_t)k * k3D + lane];   // coalesced 256B
        }
    }

#pragma unroll
    for (int r = 0; r < QPW; ++r)
        ctx[((size_t)b * kS + qi[r]) * kD + h * kHD + lane] =
            vsum[r] / (float)cnt[r];
}

// ---------------------------------------------------------------------------
extern "C" void kernel_launch(void* const* d_in, const int* in_sizes, int n_in,
                              void* d_out, int out_size, void* d_ws, size_t ws_size,
                              hipStream_t stream)
{
    const float* x     = (const float*)d_in[0];
    const float* W_qkv = (const float*)d_in[1];
    const float* b_qkv = (const float*)d_in[2];
    const float* W_o   = (const float*)d_in[3];
    const float* b_o   = (const float*)d_in[4];
    float* out = (float*)d_out;

    // workspace carve: qkv [8192][2304] (75.5 MB) + ctx [8192][768] (25 MB)
    float* qkv = (float*)d_ws;
    float* ctx = qkv + (size_t)kB * kS * k3D;

    // 1) qkv = x @ W_qkv + b_qkv      (M=8192, N=2304, K=768)
    {
        dim3 grid(k3D / 128, (kB * kS) / 128);
        gemm_bias_kernel<128, 128, 16, 8, 8><<<grid, 256, 0, stream>>>(
            x, W_qkv, b_qkv, qkv, kB * kS, k3D, kD);
    }
    // 2) attention (exact tie-averaged argmax == faithful fp32 softmax here)
    {
        dim3 grid(kS / 16, kH, kB);
        attn_select_kernel<<<grid, 256, 0, stream>>>(qkv, ctx);
    }
    // 3) out = ctx @ W_o + b_o        (M=8192, N=768, K=768)
    {
        dim3 grid(kD / 128, (kB * kS) / 64);
        gemm_bias_kernel<64, 128, 16, 4, 8><<<grid, 256, 0, stream>>>(
            ctx, W_o, b_o, out, kB * kS, kD, kD);
    }
}